// Round 3
// baseline (156.272 us; speedup 1.0000x reference)
//
#include <hip/hip_runtime.h>
#include <hip/hip_bf16.h>
#include <math.h>

#define TT 4096
#define BB 32
#define HH 512
#define CC 32000
#define NSLAB 256    // k1 blocks; each handles 512 consecutive rows (16 t * 32 b) = 1MB contiguous
#define NQ 4         // h-quarters in k3

// ws layout (float offsets)
#define WS_CTX    0          // 32*512 = 16384 floats (k2->k3)
#define WS_LPART  16384      // 32*256 = 8192 floats (k1->k2)
#define WS_BIG    24576      // ctx_part 32*256*512 = 4,194,304 f (k1->k2), then out_part 4*32*32000 f (k3->k4)

__device__ __forceinline__ float dot4(const float4 a, const float4 b) {
  return fmaf(a.w, b.w, fmaf(a.z, b.z, fmaf(a.y, b.y, fmaf(a.x, b.x, 0.f))));
}

// ---------------- k1: fused score + weighted partial sums ------------------
// 256 blocks x 512 threads (8 waves). Block = 1MB contiguous slab of dec
// (rows in (t*32+b) order). Wave w takes rows r = w + 8i; b = (w+8(i&3))&31,
// so acc slot i&3 is compile-time and waves own disjoint b's -> no LDS.
__global__ __launch_bounds__(512) void k1_partials(
    const float* __restrict__ dec, const float* __restrict__ aw,
    const float* __restrict__ abp,
    float* __restrict__ ctx_part, float* __restrict__ l_part)
{
  const int slab = blockIdx.x;
  const int tid  = threadIdx.x;
  const int wv = tid >> 6, ln = tid & 63;
  const float ab = abp[0];
  const float4 aw0 = *(const float4*)(aw + ln*8);
  const float4 aw1 = *(const float4*)(aw + ln*8 + 4);

  float4 c0[4], c1[4];
  float l[4];
  #pragma unroll
  for (int s = 0; s < 4; ++s) {
    c0[s] = make_float4(0.f,0.f,0.f,0.f);
    c1[s] = make_float4(0.f,0.f,0.f,0.f);
    l[s] = 0.f;
  }

  // wave base row = slab*512 + wv; row step 8 -> 8*HH floats
  const float* base = dec + ((size_t)slab*512 + wv)*HH + (size_t)ln*8;
  for (int ii = 0; ii < 64; ii += 8) {
    float4 x0[8], x1[8];
    #pragma unroll
    for (int j = 0; j < 8; ++j) {
      const float* p = base + (size_t)(ii + j) * (8*HH);
      x0[j] = *(const float4*)p;
      x1[j] = *(const float4*)(p + 4);
    }
    #pragma unroll
    for (int j = 0; j < 8; ++j) {
      float d = dot4(x0[j], aw0) + dot4(x1[j], aw1);
      #pragma unroll
      for (int off = 32; off > 0; off >>= 1) d += __shfl_xor(d, off);
      const float ex = __expf(2.f*(d + ab));
      const float th = 1.f - 2.f*__builtin_amdgcn_rcpf(ex + 1.f);
      const float w  = __expf(th);
      const int s = j & 3;   // (ii+j)&3 == j&3 since ii%8==0
      l[s] += w;
      c0[s].x = fmaf(w, x0[j].x, c0[s].x); c0[s].y = fmaf(w, x0[j].y, c0[s].y);
      c0[s].z = fmaf(w, x0[j].z, c0[s].z); c0[s].w = fmaf(w, x0[j].w, c0[s].w);
      c1[s].x = fmaf(w, x1[j].x, c1[s].x); c1[s].y = fmaf(w, x1[j].y, c1[s].y);
      c1[s].z = fmaf(w, x1[j].z, c1[s].z); c1[s].w = fmaf(w, x1[j].w, c1[s].w);
    }
  }

  // wave w owns b = wv + 8*s; write partials (coalesced 2KB per slice)
  #pragma unroll
  for (int s = 0; s < 4; ++s) {
    const int b = wv + 8*s;
    const size_t pp = (size_t)b*NSLAB + slab;
    *(float4*)(ctx_part + pp*HH + ln*8)     = c0[s];
    *(float4*)(ctx_part + pp*HH + ln*8 + 4) = c1[s];
    if (ln == 0) l_part[pp] = l[s];
  }
}

// ---------------- k2: combine slab partials -> normalized context -----------
// grid (b=32, q=4), 128 threads: strip = tid>>5 covers 64 slabs, hf = tid&31.
__global__ __launch_bounds__(128) void k2_combine(
    const float* __restrict__ ctx_part, const float* __restrict__ l_part,
    float* __restrict__ ctx)
{
  const int b = blockIdx.x, q = blockIdx.y;
  const int tid = threadIdx.x;
  const int strip = tid >> 5;
  const int hf = tid & 31;
  const int h = q*128 + hf*4;

  float4 a = make_float4(0.f,0.f,0.f,0.f);
  const float* basep = ctx_part + ((size_t)b*NSLAB + strip*64)*HH + h;
  #pragma unroll 8
  for (int p = 0; p < 64; ++p) {
    const float4 v = *(const float4*)(basep + (size_t)p*HH);
    a.x += v.x; a.y += v.y; a.z += v.z; a.w += v.w;
  }

  __shared__ float4 s_red[4][32];
  __shared__ float s_L;
  s_red[strip][hf] = a;

  if (tid < 64) {
    float L = 0.f;
    #pragma unroll
    for (int k = 0; k < 4; ++k) L += l_part[(size_t)b*NSLAB + tid + 64*k];
    #pragma unroll
    for (int off = 32; off > 0; off >>= 1) L += __shfl_xor(L, off);
    if (tid == 0) s_L = L;
  }
  __syncthreads();

  if (strip == 0) {
    float4 r = s_red[0][hf];
    #pragma unroll
    for (int w2 = 1; w2 < 4; ++w2) {
      const float4 v = s_red[w2][hf];
      r.x += v.x; r.y += v.y; r.z += v.z; r.w += v.w;
    }
    const float inv = 1.f / s_L;
    *(float4*)(ctx + (size_t)b*HH + h) =
        make_float4(r.x*inv, r.y*inv, r.z*inv, r.w*inv);
  }
}

// ---------------- k3: out_part = ctx @ out_w^T over h-quarters --------------
__global__ __launch_bounds__(256) void k3_matmul(
    const float* __restrict__ ctx, const float* __restrict__ ow,
    float* __restrict__ out_part)
{
  const int c = blockIdx.x * 256 + threadIdx.x;
  const int q = blockIdx.y;
  const int h0 = q * 128;
  const float* wrow = ow + (size_t)c * HH + h0;
  const float* cb = ctx + h0;
  float acc[BB];
  #pragma unroll
  for (int b = 0; b < BB; ++b) acc[b] = 0.f;
  #pragma unroll 4
  for (int hh = 0; hh < 128; hh += 4) {
    const float4 w4 = *(const float4*)(wrow + hh);
    #pragma unroll
    for (int b = 0; b < BB; ++b) {
      const float4 c4 = *(const float4*)(cb + (size_t)b*HH + hh);
      acc[b] = fmaf(w4.w, c4.w, fmaf(w4.z, c4.z, fmaf(w4.y, c4.y, fmaf(w4.x, c4.x, acc[b]))));
    }
  }
  float* op = out_part + (size_t)q * ((size_t)BB*CC);
  #pragma unroll
  for (int b = 0; b < BB; ++b) op[(size_t)b*CC + c] = acc[b];
}

// ---------------- k4: sum quarters + bias -> d_out --------------------------
__global__ __launch_bounds__(256) void k4_final(
    const float* __restrict__ out_part, const float* __restrict__ ob,
    float* __restrict__ out)
{
  const size_t i = ((size_t)blockIdx.x * 256 + threadIdx.x) * 4;
  float4 r = *(const float4*)(out_part + i);
  #pragma unroll
  for (int q = 1; q < NQ; ++q) {
    const float4 p = *(const float4*)(out_part + (size_t)q*((size_t)BB*CC) + i);
    r.x += p.x; r.y += p.y; r.z += p.z; r.w += p.w;
  }
  const int cIdx = (int)(i % CC);
  const float4 b4 = *(const float4*)(ob + cIdx);
  *(float4*)(out + i) = make_float4(r.x+b4.x, r.y+b4.y, r.z+b4.z, r.w+b4.w);
}

extern "C" void kernel_launch(void* const* d_in, const int* in_sizes, int n_in,
                              void* d_out, int out_size, void* d_ws, size_t ws_size,
                              hipStream_t stream) {
  const float* dec = (const float*)d_in[0];
  const float* aw  = (const float*)d_in[1];
  const float* ab  = (const float*)d_in[2];
  const float* ow  = (const float*)d_in[3];
  const float* ob  = (const float*)d_in[4];
  float* out = (float*)d_out;
  float* ws  = (float*)d_ws;
  float* ctx   = ws + WS_CTX;
  float* lpart = ws + WS_LPART;
  float* big   = ws + WS_BIG;   // ctx_part for k1/k2, reused as out_part for k3/k4

  k1_partials<<<dim3(NSLAB), 512, 0, stream>>>(dec, aw, ab, big, lpart);
  k2_combine<<<dim3(BB, 4), 128, 0, stream>>>(big, lpart, ctx);
  k3_matmul<<<dim3(CC/256, NQ), 256, 0, stream>>>(ctx, ow, big);
  k4_final<<<dim3((BB*CC)/(256*4)), 256, 0, stream>>>(big, ob, out);
}

// Round 4
// 139.650 us; speedup vs baseline: 1.1190x; 1.1190x over previous
//
#include <hip/hip_runtime.h>
#include <hip/hip_bf16.h>
#include <math.h>

#define TT 4096
#define BB 32
#define HH 512
#define CC 32000
#define NCHUNK 64   // t-chunks (TT/TPC)
#define TPC 64      // t per chunk (4 waves x 16 rows)

// ws layout (float offsets)
#define WS_CTX    0          // 32*512 = 16384 floats (k2->k3)
#define WS_LPART  16384      // 32*64 = 2048 floats (k1->k2)
#define WS_BIG    18432      // ctx_part 32*64*512=1,048,576 f; then out_part 2*32*32000=2,048,000 f

__device__ __forceinline__ float dot4(const float4 a, const float4 b) {
  return fmaf(a.w, b.w, fmaf(a.z, b.z, fmaf(a.y, b.y, fmaf(a.x, b.x, 0.f))));
}

// ---------------- k1: fused score + weighted partial sums ------------------
// grid (chunk=64, b=32), block 256 (4 waves), wave = 16 rows of t.
// Software-pipelined in batches of 4 rows: loads for batch n+1 are issued
// BEFORE the butterfly/exp tail of batch n, so the wave always has 8KB of
// reads in flight (the tail is ~400cy of serial swizzle/exp with zero loads
// outstanding in R1-R3 -> ~25% load duty -> 2.2 TB/s; this fixes that).
__global__ __launch_bounds__(256) void k1_partials(
    const float* __restrict__ dec, const float* __restrict__ aw,
    const float* __restrict__ abp,
    float* __restrict__ ctx_part, float* __restrict__ l_part)
{
  const int chunk = blockIdx.x;
  const int b     = blockIdx.y;
  const int tid   = threadIdx.x;
  const int wv = tid >> 6, ln = tid & 63;
  const float ab = abp[0];
  const float4 aw0 = *(const float4*)(aw + ln*8);
  const float4 aw1 = *(const float4*)(aw + ln*8 + 4);

  const size_t rowstep = (size_t)BB*HH;
  const float* base = dec + ((size_t)(chunk*TPC + wv*16)*BB + b)*HH + (size_t)ln*8;

  float4 A0[4], A1[4], B0[4], B1[4];
  float4 c0 = make_float4(0.f,0.f,0.f,0.f), c1 = make_float4(0.f,0.f,0.f,0.f);
  float l = 0.f;

  auto LD = [&](float4* X0, float4* X1, int i0) {
    #pragma unroll
    for (int j = 0; j < 4; ++j) {
      const float* p = base + (size_t)(i0 + j) * rowstep;
      X0[j] = *(const float4*)p;
      X1[j] = *(const float4*)(p + 4);
    }
  };
  auto CMP = [&](const float4* X0, const float4* X1) {
    float d[4];
    #pragma unroll
    for (int j = 0; j < 4; ++j) d[j] = dot4(X0[j], aw0) + dot4(X1[j], aw1);
    // 4 independent butterflies interleaved -> swizzle latency overlapped
    #pragma unroll
    for (int off = 32; off > 0; off >>= 1) {
      #pragma unroll
      for (int j = 0; j < 4; ++j) d[j] += __shfl_xor(d[j], off);
    }
    #pragma unroll
    for (int j = 0; j < 4; ++j) {
      const float ex = __expf(2.f*(d[j] + ab));
      const float th = 1.f - 2.f*__builtin_amdgcn_rcpf(ex + 1.f);
      const float w  = __expf(th);
      l += w;
      c0.x = fmaf(w, X0[j].x, c0.x); c0.y = fmaf(w, X0[j].y, c0.y);
      c0.z = fmaf(w, X0[j].z, c0.z); c0.w = fmaf(w, X0[j].w, c0.w);
      c1.x = fmaf(w, X1[j].x, c1.x); c1.y = fmaf(w, X1[j].y, c1.y);
      c1.z = fmaf(w, X1[j].z, c1.z); c1.w = fmaf(w, X1[j].w, c1.w);
    }
  };

  LD(A0, A1, 0);
  LD(B0, B1, 4);
  CMP(A0, A1);
  LD(A0, A1, 8);
  CMP(B0, B1);
  LD(B0, B1, 12);
  CMP(A0, A1);
  CMP(B0, B1);

  __shared__ float s_ctx[4][HH];
  __shared__ float s_l[4];
  *(float4*)&s_ctx[wv][ln*8]     = c0;
  *(float4*)&s_ctx[wv][ln*8 + 4] = c1;
  if (ln == 0) s_l[wv] = l;
  __syncthreads();
  if (tid < 128) {
    const int h = tid * 4;
    float4 a = make_float4(0.f,0.f,0.f,0.f);
    #pragma unroll
    for (int w2 = 0; w2 < 4; ++w2) {
      const float4 v = *(const float4*)&s_ctx[w2][h];
      a.x += v.x; a.y += v.y; a.z += v.z; a.w += v.w;
    }
    const size_t pp = (size_t)b*NCHUNK + chunk;
    *(float4*)(ctx_part + pp*HH + h) = a;
    if (tid == 0) l_part[pp] = s_l[0] + s_l[1] + s_l[2] + s_l[3];
  }
}

// ---------------- k2: combine partials -> normalized context ----------------
__global__ __launch_bounds__(128) void k2_combine(
    const float* __restrict__ ctx_part, const float* __restrict__ l_part,
    float* __restrict__ ctx)
{
  const int b = blockIdx.x;
  const int h = threadIdx.x * 4;
  float L = 0.f;
  for (int p = 0; p < NCHUNK; ++p) L += l_part[b*NCHUNK + p];
  float4 a = make_float4(0.f,0.f,0.f,0.f);
  for (int p = 0; p < NCHUNK; ++p) {
    const float4 v = *(const float4*)(ctx_part + ((size_t)b*NCHUNK + p)*HH + h);
    a.x += v.x; a.y += v.y; a.z += v.z; a.w += v.w;
  }
  const float inv = 1.f / L;
  *(float4*)(ctx + b*HH + h) = make_float4(a.x*inv, a.y*inv, a.z*inv, a.w*inv);
}

// ---------------- k3: out = ctx @ out_w^T (partials over h-halves) ----------
__global__ __launch_bounds__(128) void k3_matmul(
    const float* __restrict__ ctx, const float* __restrict__ ow,
    float* __restrict__ out_part)
{
  const int c = blockIdx.x * 128 + threadIdx.x;
  const int half = blockIdx.y;            // h in [half*256, half*256+256)
  const int h0 = half * 256;
  const float* wrow = ow + (size_t)c * HH + h0;
  const float* cb = ctx + h0;             // uniform across block
  float acc[BB];
  #pragma unroll
  for (int b = 0; b < BB; ++b) acc[b] = 0.f;
  for (int hh = 0; hh < 256; hh += 4) {
    const float4 w4 = *(const float4*)(wrow + hh);
    #pragma unroll
    for (int b = 0; b < BB; ++b) {
      const float4 c4 = *(const float4*)(cb + (size_t)b*HH + hh);
      acc[b] = fmaf(w4.w, c4.w, fmaf(w4.z, c4.z, fmaf(w4.y, c4.y, fmaf(w4.x, c4.x, acc[b]))));
    }
  }
  float* op = out_part + (size_t)half * ((size_t)BB*CC);
  #pragma unroll
  for (int b = 0; b < BB; ++b) op[(size_t)b*CC + c] = acc[b];
}

// ---------------- k4: sum halves + bias -> d_out ---------------------------
__global__ __launch_bounds__(256) void k4_final(
    const float* __restrict__ out_part, const float* __restrict__ ob,
    float* __restrict__ out)
{
  const size_t i = ((size_t)blockIdx.x * 256 + threadIdx.x) * 4;
  const float4 p0 = *(const float4*)(out_part + i);
  const float4 p1 = *(const float4*)(out_part + (size_t)BB*CC + i);
  const int cIdx = (int)(i % CC);
  const float4 b4 = *(const float4*)(ob + cIdx);
  const float4 r = make_float4(p0.x+p1.x+b4.x, p0.y+p1.y+b4.y,
                               p0.z+p1.z+b4.z, p0.w+p1.w+b4.w);
  *(float4*)(out + i) = r;
}

extern "C" void kernel_launch(void* const* d_in, const int* in_sizes, int n_in,
                              void* d_out, int out_size, void* d_ws, size_t ws_size,
                              hipStream_t stream) {
  const float* dec = (const float*)d_in[0];
  const float* aw  = (const float*)d_in[1];
  const float* ab  = (const float*)d_in[2];
  const float* ow  = (const float*)d_in[3];
  const float* ob  = (const float*)d_in[4];
  float* out = (float*)d_out;
  float* ws  = (float*)d_ws;
  float* ctx   = ws + WS_CTX;
  float* lpart = ws + WS_LPART;
  float* big   = ws + WS_BIG;   // ctx_part for k1/k2, reused as out_part for k3/k4

  k1_partials<<<dim3(NCHUNK, BB), 256, 0, stream>>>(dec, aw, ab, big, lpart);
  k2_combine<<<dim3(BB), 128, 0, stream>>>(big, lpart, ctx);
  k3_matmul<<<dim3(CC/128, 2), 128, 0, stream>>>(ctx, ow, big);
  k4_final<<<dim3((BB*CC)/(256*4)), 256, 0, stream>>>(big, ob, out);
}